// Round 1
// baseline (2812.019 us; speedup 1.0000x reference)
//
#include <hip/hip_runtime.h>
#include <math.h>

#define B_  4
#define N_  1024
#define D_  512
#define H_  8
#define DH_ 64
#define TC_ 512
#define AB_ 16
#define EPS_ 1e-5f
#define NEG_ 1e6f

// ---------------------------------------------------------------------------
// FiLM precompute: film[b, c] = sum_j silu(time[b, j]) * Wt[c, j] + bt[c]
// film layout: [B, 2*D] ; scale = film[b, 0:D], shift = film[b, D:2D]
// ---------------------------------------------------------------------------
__global__ void film_kernel(const float* __restrict__ time_in,
                            const float* __restrict__ Wt,
                            const float* __restrict__ bt,
                            float* __restrict__ film) {
    int idx = blockIdx.x * blockDim.x + threadIdx.x;   // 0 .. B*2D-1 = 4095
    int b = idx >> 10;
    int c = idx & 1023;
    const float* trow = time_in + b * TC_;
    const float* wrow = Wt + (size_t)c * TC_;
    float acc = bt[c];
    for (int j = 0; j < TC_; ++j) {
        float tv = trow[j];
        float s = tv / (1.f + __expf(-tv));   // silu
        acc += s * wrow[j];
    }
    film[idx] = acc;
}

// ---------------------------------------------------------------------------
// LayerNorm + FiLM + seq_mask:  xn = LN(x)*gamma * (scale+1) + shift, * mask
// one block (256 threads) per row of [B*N, D]
// ---------------------------------------------------------------------------
__global__ __launch_bounds__(256)
void ln_film_kernel(const float* __restrict__ x,
                    const float* __restrict__ gamma,
                    const float* __restrict__ film,
                    const float* __restrict__ seq_mask,
                    float* __restrict__ xn) {
    int row = blockIdx.x;           // b*N + i
    int b = row >> 10;
    int t = threadIdx.x;
    const float* xr = x + (size_t)row * D_;
    float v0 = xr[t];
    float v1 = xr[t + 256];
    float s = v0 + v1;
    float sq = v0 * v0 + v1 * v1;
    int lane = t & 63, wave = t >> 6;
    #pragma unroll
    for (int off = 32; off; off >>= 1) {
        s  += __shfl_down(s, off);
        sq += __shfl_down(sq, off);
    }
    __shared__ float rs[4], rq[4];
    if (lane == 0) { rs[wave] = s; rq[wave] = sq; }
    __syncthreads();
    float mu  = (rs[0] + rs[1] + rs[2] + rs[3]) * (1.f / D_);
    float ex2 = (rq[0] + rq[1] + rq[2] + rq[3]) * (1.f / D_);
    float var = ex2 - mu * mu;
    float rstd = rsqrtf(var + EPS_);
    float mrow = seq_mask[row];
    const float* scale = film + (size_t)b * 2 * D_;
    const float* shift = scale + D_;
    {
        int d = t;
        float val = (v0 - mu) * rstd * gamma[d];
        val = val * (scale[d] + 1.f) + shift[d];
        xn[(size_t)row * D_ + d] = val * mrow;
    }
    {
        int d = t + 256;
        float val = (v1 - mu) * rstd * gamma[d];
        val = val * (scale[d] + 1.f) + shift[d];
        xn[(size_t)row * D_ + d] = val * mrow;
    }
}

// ---------------------------------------------------------------------------
// Generic C[M,Nn] = A[M,K] @ Bm[Nn,K]^T  (both row-major), optional per-row mask
// 64x64 tile, BK=16, 256 threads, 4x4 micro-tile per thread.
// ---------------------------------------------------------------------------
__global__ __launch_bounds__(256)
void gemm_bt_kernel(const float* __restrict__ A,
                    const float* __restrict__ Bm,
                    float* __restrict__ C,
                    int M, int Nn, int K,
                    const float* __restrict__ rowmask) {
    __shared__ float As[16][65];
    __shared__ float Bs[16][65];
    int tid = threadIdx.x;
    int tx = tid & 15;          // n sub-tile
    int ty = tid >> 4;          // m sub-tile
    int n0 = blockIdx.x * 64;
    int m0 = blockIdx.y * 64;
    float c[4][4] = {};
    int kk0 = tid & 15;
    int rr  = tid >> 4;
    for (int k0 = 0; k0 < K; k0 += 16) {
        #pragma unroll
        for (int l = 0; l < 4; ++l) {
            int mm = rr + l * 16;
            As[kk0][mm] = A[(size_t)(m0 + mm) * K + k0 + kk0];
            Bs[kk0][mm] = Bm[(size_t)(n0 + mm) * K + k0 + kk0];
        }
        __syncthreads();
        #pragma unroll
        for (int kk = 0; kk < 16; ++kk) {
            float a[4], bv[4];
            #pragma unroll
            for (int i = 0; i < 4; ++i) a[i] = As[kk][ty * 4 + i];
            #pragma unroll
            for (int j = 0; j < 4; ++j) bv[j] = Bs[kk][tx * 4 + j];
            #pragma unroll
            for (int i = 0; i < 4; ++i)
                #pragma unroll
                for (int j = 0; j < 4; ++j)
                    c[i][j] += a[i] * bv[j];
        }
        __syncthreads();
    }
    #pragma unroll
    for (int i = 0; i < 4; ++i) {
        int m = m0 + ty * 4 + i;
        float mk = rowmask ? rowmask[m] : 1.f;
        #pragma unroll
        for (int j = 0; j < 4; ++j) {
            C[(size_t)m * Nn + n0 + tx * 4 + j] = c[i][j] * mk;
        }
    }
}

// ---------------------------------------------------------------------------
// Attention: one block per (b, i), all H=8 heads.
//   scores[h][j] = q[b,h,i,:]·k[b,h,j,:]*DH^-0.5 + sum_a bias[b,a,i,j]*Wb[h,a]
//                  + bb[h] - (1-m)*NEG  ;  softmax over j ; out = P @ V
// q layout:  [B*N, H*DH]   kv layout: [B*N, 2*H*DH] (k first, v second)
// ---------------------------------------------------------------------------
__global__ __launch_bounds__(256)
void attn_kernel(const float* __restrict__ q,
                 const float* __restrict__ kv,
                 const float* __restrict__ attn_bias,
                 const float* __restrict__ seq_mask,
                 const float* __restrict__ Wb,
                 const float* __restrict__ bb,
                 float* __restrict__ att) {
    __shared__ float qs[512];
    __shared__ float sc[8][1024];
    __shared__ float wbs[8][16];
    __shared__ float bbs[8];
    __shared__ float red[4];
    __shared__ float rden[8];

    int blk = blockIdx.x;
    int b = blk >> 10;
    int i = blk & 1023;
    int t = threadIdx.x;
    int lane = t & 63, wave = t >> 6;

    qs[t]       = q[(size_t)blk * 512 + t] * 0.125f;        // DH^-0.5 = 1/8
    qs[t + 256] = q[(size_t)blk * 512 + t + 256] * 0.125f;
    if (t < 128) wbs[t >> 4][t & 15] = Wb[t];
    if (t < 8)   bbs[t] = bb[t];
    float mq = seq_mask[blk];
    __syncthreads();

    // ---- phase 1: scores ----
    for (int jj = 0; jj < 4; ++jj) {
        int j = jj * 256 + t;
        float bias[8];
        #pragma unroll
        for (int h = 0; h < 8; ++h) bias[h] = bbs[h];
        const float* abp = attn_bias + ((size_t)(b * AB_) * N_ + i) * N_ + j;
        #pragma unroll
        for (int a = 0; a < AB_; ++a) {
            float ab = abp[(size_t)a * N_ * N_];
            #pragma unroll
            for (int h = 0; h < 8; ++h) bias[h] += ab * wbs[h][a];
        }
        float mk = seq_mask[b * N_ + j];
        float pen = (1.f - mq * mk) * NEG_;
        const float* krow = kv + (size_t)(b * N_ + j) * 1024;
        for (int h = 0; h < 8; ++h) {
            const float* kp = krow + h * 64;
            const float* qp = qs + h * 64;
            float acc = 0.f;
            #pragma unroll
            for (int d = 0; d < 64; ++d) acc += qp[d] * kp[d];
            sc[h][j] = acc + bias[h] - pen;
        }
    }
    __syncthreads();

    // ---- phase 2: softmax per head ----
    for (int h = 0; h < 8; ++h) {
        float m = -1e30f;
        #pragma unroll
        for (int jj = 0; jj < 4; ++jj) m = fmaxf(m, sc[h][jj * 256 + t]);
        #pragma unroll
        for (int off = 32; off; off >>= 1) m = fmaxf(m, __shfl_down(m, off));
        if (lane == 0) red[wave] = m;
        __syncthreads();
        m = fmaxf(fmaxf(red[0], red[1]), fmaxf(red[2], red[3]));
        float ssum = 0.f;
        #pragma unroll
        for (int jj = 0; jj < 4; ++jj) {
            int j = jj * 256 + t;
            float e = __expf(sc[h][j] - m);
            sc[h][j] = e;
            ssum += e;
        }
        #pragma unroll
        for (int off = 32; off; off >>= 1) ssum += __shfl_down(ssum, off);
        __syncthreads();          // everyone done reading red (max)
        if (lane == 0) red[wave] = ssum;
        __syncthreads();
        if (t == 0) rden[h] = 1.f / (red[0] + red[1] + red[2] + red[3]);
        __syncthreads();          // rden written; red free for next h
    }

    // ---- phase 3: out = P @ V ----
    for (int hh = 0; hh < 2; ++hh) {
        int h = hh * 4 + (t >> 6);
        int d = t & 63;
        float acc = 0.f;
        const float* vbase = kv + (size_t)b * N_ * 1024 + 512 + h * 64 + d;
        #pragma unroll 4
        for (int j = 0; j < N_; ++j) {
            acc += sc[h][j] * vbase[(size_t)j * 1024];
        }
        att[(size_t)blk * 512 + h * 64 + d] = acc * rden[h];
    }
}

// ---------------------------------------------------------------------------
extern "C" void kernel_launch(void* const* d_in, const int* in_sizes, int n_in,
                              void* d_out, int out_size, void* d_ws, size_t ws_size,
                              hipStream_t stream) {
    const float* x         = (const float*)d_in[0];
    const float* time_in   = (const float*)d_in[1];
    const float* attn_bias = (const float*)d_in[2];
    const float* seq_mask  = (const float*)d_in[3];
    const float* gamma     = (const float*)d_in[4];
    const float* Wt        = (const float*)d_in[5];
    const float* bt        = (const float*)d_in[6];
    const float* Wq        = (const float*)d_in[7];
    const float* Wkv       = (const float*)d_in[8];
    const float* Wo        = (const float*)d_in[9];
    const float* Wb        = (const float*)d_in[10];
    const float* bb        = (const float*)d_in[11];
    float* out = (float*)d_out;

    char* ws = (char*)d_ws;
    const size_t MB8 = 8u * 1024u * 1024u;
    float* film = (float*)ws;                       // 16 KB
    float* xn   = (float*)(ws + 16384);             // 8 MB  [4096,512]
    float* qb   = (float*)(ws + 16384 + MB8);       // 8 MB  [4096,512]
    float* kvb  = (float*)(ws + 16384 + 2 * MB8);   // 16 MB [4096,1024]
    float* att  = (float*)(ws + 16384 + 4 * MB8);   // 8 MB  [4096,512]

    film_kernel<<<16, 256, 0, stream>>>(time_in, Wt, bt, film);
    ln_film_kernel<<<4096, 256, 0, stream>>>(x, gamma, film, seq_mask, xn);
    dim3 gq(512 / 64, 4096 / 64);
    gemm_bt_kernel<<<gq, 256, 0, stream>>>(xn, Wq, qb, 4096, 512, 512, nullptr);
    dim3 gkv(1024 / 64, 4096 / 64);
    gemm_bt_kernel<<<gkv, 256, 0, stream>>>(x, Wkv, kvb, 4096, 1024, 512, nullptr);
    attn_kernel<<<4096, 256, 0, stream>>>(qb, kvb, attn_bias, seq_mask, Wb, bb, att);
    dim3 go(512 / 64, 4096 / 64);
    gemm_bt_kernel<<<go, 256, 0, stream>>>(att, Wo, out, 4096, 512, 512, seq_mask);
}

// Round 3
// 806.623 us; speedup vs baseline: 3.4862x; 3.4862x over previous
//
#include <hip/hip_runtime.h>
#include <hip/hip_bf16.h>
#include <math.h>

#define B_  4
#define N_  1024
#define D_  512
#define H_  8
#define DH_ 64
#define TC_ 512
#define AB_ 16
#define EPS_ 1e-5f
#define NEG_ 1e6f

// ---------------------------------------------------------------------------
// FiLM precompute: film[b, c] = sum_j silu(time[b, j]) * Wt[c, j] + bt[c]
// ---------------------------------------------------------------------------
__global__ void film_kernel(const float* __restrict__ time_in,
                            const float* __restrict__ Wt,
                            const float* __restrict__ bt,
                            float* __restrict__ film) {
    int idx = blockIdx.x * blockDim.x + threadIdx.x;   // 0 .. B*2D-1 = 4095
    int b = idx >> 10;
    int c = idx & 1023;
    const float* trow = time_in + b * TC_;
    const float* wrow = Wt + (size_t)c * TC_;
    float acc = bt[c];
    for (int j = 0; j < TC_; ++j) {
        float tv = trow[j];
        float s = tv / (1.f + __expf(-tv));   // silu
        acc += s * wrow[j];
    }
    film[idx] = acc;
}

// ---------------------------------------------------------------------------
// LayerNorm + FiLM + seq_mask
// ---------------------------------------------------------------------------
__global__ __launch_bounds__(256)
void ln_film_kernel(const float* __restrict__ x,
                    const float* __restrict__ gamma,
                    const float* __restrict__ film,
                    const float* __restrict__ seq_mask,
                    float* __restrict__ xn) {
    int row = blockIdx.x;           // b*N + i
    int b = row >> 10;
    int t = threadIdx.x;
    const float* xr = x + (size_t)row * D_;
    float v0 = xr[t];
    float v1 = xr[t + 256];
    float s = v0 + v1;
    float sq = v0 * v0 + v1 * v1;
    int lane = t & 63, wave = t >> 6;
    #pragma unroll
    for (int off = 32; off; off >>= 1) {
        s  += __shfl_down(s, off);
        sq += __shfl_down(sq, off);
    }
    __shared__ float rs[4], rq[4];
    if (lane == 0) { rs[wave] = s; rq[wave] = sq; }
    __syncthreads();
    float mu  = (rs[0] + rs[1] + rs[2] + rs[3]) * (1.f / D_);
    float ex2 = (rq[0] + rq[1] + rq[2] + rq[3]) * (1.f / D_);
    float var = ex2 - mu * mu;
    float rstd = rsqrtf(var + EPS_);
    float mrow = seq_mask[row];
    const float* scale = film + (size_t)b * 2 * D_;
    const float* shift = scale + D_;
    {
        int d = t;
        float val = (v0 - mu) * rstd * gamma[d];
        val = val * (scale[d] + 1.f) + shift[d];
        xn[(size_t)row * D_ + d] = val * mrow;
    }
    {
        int d = t + 256;
        float val = (v1 - mu) * rstd * gamma[d];
        val = val * (scale[d] + 1.f) + shift[d];
        xn[(size_t)row * D_ + d] = val * mrow;
    }
}

// ---------------------------------------------------------------------------
// Generic C[M,Nn] = A[M,K] @ Bm[Nn,K]^T, optional per-row output mask
// ---------------------------------------------------------------------------
__global__ __launch_bounds__(256)
void gemm_bt_kernel(const float* __restrict__ A,
                    const float* __restrict__ Bm,
                    float* __restrict__ C,
                    int M, int Nn, int K,
                    const float* __restrict__ rowmask) {
    __shared__ float As[16][65];
    __shared__ float Bs[16][65];
    int tid = threadIdx.x;
    int tx = tid & 15;
    int ty = tid >> 4;
    int n0 = blockIdx.x * 64;
    int m0 = blockIdx.y * 64;
    float c[4][4] = {};
    int kk0 = tid & 15;
    int rr  = tid >> 4;
    for (int k0 = 0; k0 < K; k0 += 16) {
        #pragma unroll
        for (int l = 0; l < 4; ++l) {
            int mm = rr + l * 16;
            As[kk0][mm] = A[(size_t)(m0 + mm) * K + k0 + kk0];
            Bs[kk0][mm] = Bm[(size_t)(n0 + mm) * K + k0 + kk0];
        }
        __syncthreads();
        #pragma unroll
        for (int kk = 0; kk < 16; ++kk) {
            float a[4], bv[4];
            #pragma unroll
            for (int i = 0; i < 4; ++i) a[i] = As[kk][ty * 4 + i];
            #pragma unroll
            for (int j = 0; j < 4; ++j) bv[j] = Bs[kk][tx * 4 + j];
            #pragma unroll
            for (int i = 0; i < 4; ++i)
                #pragma unroll
                for (int j = 0; j < 4; ++j)
                    c[i][j] += a[i] * bv[j];
        }
        __syncthreads();
    }
    #pragma unroll
    for (int i = 0; i < 4; ++i) {
        int m = m0 + ty * 4 + i;
        float mk = rowmask ? rowmask[m] : 1.f;
        #pragma unroll
        for (int j = 0; j < 4; ++j) {
            C[(size_t)m * Nn + n0 + tx * 4 + j] = c[i][j] * mk;
        }
    }
}

// ---------------------------------------------------------------------------
// bias projection: pb[b,h,i,j] = sum_a attn_bias[b,a,i,j]*Wb[h,a] + bb[h]
//                                - (1 - mq*mk)*NEG          (stored as bf16)
// one block per (b, i); thread t owns cols j = t*4 .. t*4+3
// ---------------------------------------------------------------------------
__global__ __launch_bounds__(256)
void bias_proj_kernel(const float* __restrict__ ab,
                      const float* __restrict__ seq_mask,
                      const float* __restrict__ Wb,
                      const float* __restrict__ bb,
                      __hip_bfloat16* __restrict__ pb) {
    __shared__ float wbs[8][16];
    __shared__ float bbs[8];
    int blk = blockIdx.x;      // b*1024 + i
    int b = blk >> 10;
    int i = blk & 1023;
    int t = threadIdx.x;
    if (t < 128) wbs[t >> 4][t & 15] = Wb[t];
    if (t < 8)   bbs[t] = bb[t];
    __syncthreads();

    float accx[8], accy[8], accz[8], accw[8];
    #pragma unroll
    for (int h = 0; h < 8; ++h) { accx[h] = accy[h] = accz[h] = accw[h] = bbs[h]; }

    const float* base = ab + ((size_t)(b * AB_) * N_ + i) * N_ + t * 4;
    #pragma unroll
    for (int a = 0; a < AB_; ++a) {
        float4 v = *(const float4*)(base + (size_t)a * N_ * N_);
        #pragma unroll
        for (int h = 0; h < 8; ++h) {
            float w = wbs[h][a];
            accx[h] += v.x * w;
            accy[h] += v.y * w;
            accz[h] += v.z * w;
            accw[h] += v.w * w;
        }
    }
    float mq = seq_mask[blk];
    float4 mk = *(const float4*)(seq_mask + b * N_ + t * 4);
    float px = (1.f - mq * mk.x) * NEG_;
    float py = (1.f - mq * mk.y) * NEG_;
    float pz = (1.f - mq * mk.z) * NEG_;
    float pw = (1.f - mq * mk.w) * NEG_;

    #pragma unroll
    for (int h = 0; h < 8; ++h) {
        __hip_bfloat16 tmp[4];
        tmp[0] = __float2bfloat16(accx[h] - px);
        tmp[1] = __float2bfloat16(accy[h] - py);
        tmp[2] = __float2bfloat16(accz[h] - pz);
        tmp[3] = __float2bfloat16(accw[h] - pw);
        size_t off = (((size_t)(b * 8 + h) * N_) + i) * N_ + t * 4;
        *(ushort4*)(pb + off) = *(ushort4*)tmp;
    }
}

// ---------------------------------------------------------------------------
// Flash attention: one block per (b, h, 64-query tile). Online softmax.
//   q layout [B*N, 512]; kv layout [B*N, 1024] (k | v); pb [B,H,N,N] bf16
// thread grid 16x16: rows ty*4+i (i<4), cols strided tx + jj*16 for S,
// contiguous tx*4+dd for O. All LDS patterns <=2-way bank aliasing.
// ---------------------------------------------------------------------------
#define LDST 68
__global__ __launch_bounds__(256, 2)
void flash_attn_kernel(const float* __restrict__ q,
                       const float* __restrict__ kv,
                       const __hip_bfloat16* __restrict__ pb,
                       float* __restrict__ att) {
    __shared__ float Qs[64][LDST];
    __shared__ float Ks[64][LDST];
    __shared__ float Vs[64][LDST];
    __shared__ float Ps[64][LDST];

    int z  = blockIdx.x;
    int it = z & 15;
    int h  = (z >> 4) & 7;
    int b  = z >> 7;
    int i0 = it * 64;
    int t  = threadIdx.x;
    int tx = t & 15;
    int ty = t >> 4;

    // stage Q tile (scaled by DH^-0.5 = 1/8)
    const float* qbase = q + ((size_t)(b * N_ + i0)) * 512 + h * 64;
    #pragma unroll
    for (int l = 0; l < 4; ++l) {
        int idx = l * 256 + t;          // float4 index 0..1023
        int r   = idx >> 4;
        int c4  = (idx & 15) * 4;
        float4 v = *(const float4*)(qbase + (size_t)r * 512 + c4);
        v.x *= 0.125f; v.y *= 0.125f; v.z *= 0.125f; v.w *= 0.125f;
        *(float4*)&Qs[r][c4] = v;
    }

    float m_r[4], l_r[4], c_o[4][4];
    #pragma unroll
    for (int i = 0; i < 4; ++i) {
        m_r[i] = -1e30f; l_r[i] = 0.f;
        #pragma unroll
        for (int d = 0; d < 4; ++d) c_o[i][d] = 0.f;
    }

    const float* kvbase = kv + (size_t)b * N_ * 1024 + h * 64;
    const __hip_bfloat16* pbbase = pb + ((size_t)((b * 8 + h) * N_) + i0) * N_;

    for (int jt = 0; jt < 16; ++jt) {
        int j0 = jt * 64;
        // ---- global loads (regs only; overlap with prev-iter compute) ----
        float4 kreg[4], vreg[4];
        #pragma unroll
        for (int l = 0; l < 4; ++l) {
            int idx = l * 256 + t;
            int r   = idx >> 4;
            int c4  = (idx & 15) * 4;
            const float* p = kvbase + (size_t)(j0 + r) * 1024 + c4;
            kreg[l] = *(const float4*)p;
            vreg[l] = *(const float4*)(p + 512);
        }
        float sreg[4][4];
        #pragma unroll
        for (int i = 0; i < 4; ++i)
            #pragma unroll
            for (int jj = 0; jj < 4; ++jj)
                sreg[i][jj] = __bfloat162float(
                    pbbase[(size_t)(ty * 4 + i) * N_ + j0 + tx + jj * 16]);

        __syncthreads();   // prev PV reads of Ks/Vs/Ps complete
        #pragma unroll
        for (int l = 0; l < 4; ++l) {
            int idx = l * 256 + t;
            int r   = idx >> 4;
            int c4  = (idx & 15) * 4;
            *(float4*)&Ks[r][c4] = kreg[l];
            *(float4*)&Vs[r][c4] = vreg[l];
        }
        __syncthreads();   // staging visible

        // ---- S = Q K^T + bias ----
        #pragma unroll
        for (int d0 = 0; d0 < 64; d0 += 4) {
            float4 a4[4], b4[4];
            #pragma unroll
            for (int i = 0; i < 4; ++i) a4[i] = *(float4*)&Qs[ty * 4 + i][d0];
            #pragma unroll
            for (int jj = 0; jj < 4; ++jj) b4[jj] = *(float4*)&Ks[tx + jj * 16][d0];
            #pragma unroll
            for (int i = 0; i < 4; ++i)
                #pragma unroll
                for (int jj = 0; jj < 4; ++jj)
                    sreg[i][jj] += a4[i].x * b4[jj].x + a4[i].y * b4[jj].y
                                 + a4[i].z * b4[jj].z + a4[i].w * b4[jj].w;
        }

        // ---- online softmax update ----
        float rm[4], alpha[4], rsum[4], preg[4][4];
        #pragma unroll
        for (int i = 0; i < 4; ++i) {
            rm[i] = fmaxf(fmaxf(sreg[i][0], sreg[i][1]),
                          fmaxf(sreg[i][2], sreg[i][3]));
        }
        #pragma unroll
        for (int off = 1; off < 16; off <<= 1) {
            #pragma unroll
            for (int i = 0; i < 4; ++i)
                rm[i] = fmaxf(rm[i], __shfl_xor(rm[i], off));
        }
        #pragma unroll
        for (int i = 0; i < 4; ++i) {
            float mn = fmaxf(m_r[i], rm[i]);
            alpha[i] = __expf(m_r[i] - mn);
            m_r[i] = mn;
            float p0 = __expf(sreg[i][0] - mn);
            float p1 = __expf(sreg[i][1] - mn);
            float p2 = __expf(sreg[i][2] - mn);
            float p3 = __expf(sreg[i][3] - mn);
            preg[i][0] = p0; preg[i][1] = p1; preg[i][2] = p2; preg[i][3] = p3;
            rsum[i] = p0 + p1 + p2 + p3;
        }
        #pragma unroll
        for (int off = 1; off < 16; off <<= 1) {
            #pragma unroll
            for (int i = 0; i < 4; ++i)
                rsum[i] += __shfl_xor(rsum[i], off);
        }
        #pragma unroll
        for (int i = 0; i < 4; ++i) {
            l_r[i] = l_r[i] * alpha[i] + rsum[i];
            #pragma unroll
            for (int d = 0; d < 4; ++d) c_o[i][d] *= alpha[i];
            #pragma unroll
            for (int jj = 0; jj < 4; ++jj)
                Ps[ty * 4 + i][tx + jj * 16] = preg[i][jj];
        }
        __syncthreads();   // Ps visible

        // ---- O += P @ V ----
        #pragma unroll 8
        for (int j = 0; j < 64; ++j) {
            float a_[4];
            #pragma unroll
            for (int i = 0; i < 4; ++i) a_[i] = Ps[ty * 4 + i][j];
            float4 bv = *(float4*)&Vs[j][tx * 4];
            #pragma unroll
            for (int i = 0; i < 4; ++i) {
                c_o[i][0] += a_[i] * bv.x;
                c_o[i][1] += a_[i] * bv.y;
                c_o[i][2] += a_[i] * bv.z;
                c_o[i][3] += a_[i] * bv.w;
            }
        }
    }

    // ---- epilogue ----
    float* obase = att + ((size_t)(b * N_ + i0)) * 512 + h * 64;
    #pragma unroll
    for (int i = 0; i < 4; ++i) {
        float inv = 1.f / l_r[i];
        float4 o;
        o.x = c_o[i][0] * inv;
        o.y = c_o[i][1] * inv;
        o.z = c_o[i][2] * inv;
        o.w = c_o[i][3] * inv;
        *(float4*)(obase + (size_t)(ty * 4 + i) * 512 + tx * 4) = o;
    }
}

// ---------------------------------------------------------------------------
extern "C" void kernel_launch(void* const* d_in, const int* in_sizes, int n_in,
                              void* d_out, int out_size, void* d_ws, size_t ws_size,
                              hipStream_t stream) {
    const float* x         = (const float*)d_in[0];
    const float* time_in   = (const float*)d_in[1];
    const float* attn_bias = (const float*)d_in[2];
    const float* seq_mask  = (const float*)d_in[3];
    const float* gamma     = (const float*)d_in[4];
    const float* Wt        = (const float*)d_in[5];
    const float* bt        = (const float*)d_in[6];
    const float* Wq        = (const float*)d_in[7];
    const float* Wkv       = (const float*)d_in[8];
    const float* Wo        = (const float*)d_in[9];
    const float* Wb        = (const float*)d_in[10];
    const float* bb        = (const float*)d_in[11];
    float* out = (float*)d_out;

    char* ws = (char*)d_ws;
    const size_t MB8 = 8u * 1024u * 1024u;
    float* film = (float*)ws;                              // 16 KB
    float* xn   = (float*)(ws + 16384);                    // 8 MB
    float* qb   = (float*)(ws + 16384 + MB8);              // 8 MB
    float* kvb  = (float*)(ws + 16384 + 2 * MB8);          // 16 MB
    float* att  = (float*)(ws + 16384 + 4 * MB8);          // 8 MB
    __hip_bfloat16* pb = (__hip_bfloat16*)(ws + 16384 + 5 * MB8); // 64 MB

    film_kernel<<<16, 256, 0, stream>>>(time_in, Wt, bt, film);
    ln_film_kernel<<<4096, 256, 0, stream>>>(x, gamma, film, seq_mask, xn);
    dim3 gq(512 / 64, 4096 / 64);
    gemm_bt_kernel<<<gq, 256, 0, stream>>>(xn, Wq, qb, 4096, 512, 512, nullptr);
    dim3 gkv(1024 / 64, 4096 / 64);
    gemm_bt_kernel<<<gkv, 256, 0, stream>>>(x, Wkv, kvb, 4096, 1024, 512, nullptr);
    bias_proj_kernel<<<4096, 256, 0, stream>>>(attn_bias, seq_mask, Wb, bb, pb);
    flash_attn_kernel<<<512, 256, 0, stream>>>(qb, kvb, pb, att);
    dim3 go(512 / 64, 4096 / 64);
    gemm_bt_kernel<<<go, 256, 0, stream>>>(att, Wo, out, 4096, 512, 512, seq_mask);
}

// Round 4
// 676.818 us; speedup vs baseline: 4.1548x; 1.1918x over previous
//
#include <hip/hip_runtime.h>
#include <hip/hip_bf16.h>
#include <math.h>

#define B_  4
#define N_  1024
#define D_  512
#define H_  8
#define DH_ 64
#define TC_ 512
#define AB_ 16
#define EPS_ 1e-5f
#define NEG_ 1e6f

typedef _Float16 half8v __attribute__((ext_vector_type(8)));
typedef _Float16 half4v __attribute__((ext_vector_type(4)));
typedef float floatx4 __attribute__((ext_vector_type(4)));

// ---------------------------------------------------------------------------
// FiLM precompute: film[b, c] = sum_j silu(time[b, j]) * Wt[c, j] + bt[c]
// ---------------------------------------------------------------------------
__global__ void film_kernel(const float* __restrict__ time_in,
                            const float* __restrict__ Wt,
                            const float* __restrict__ bt,
                            float* __restrict__ film) {
    int idx = blockIdx.x * blockDim.x + threadIdx.x;   // 0 .. B*2D-1 = 4095
    int b = idx >> 10;
    int c = idx & 1023;
    const float* trow = time_in + b * TC_;
    const float* wrow = Wt + (size_t)c * TC_;
    float acc = bt[c];
    for (int j = 0; j < TC_; ++j) {
        float tv = trow[j];
        float s = tv / (1.f + __expf(-tv));   // silu
        acc += s * wrow[j];
    }
    film[idx] = acc;
}

// ---------------------------------------------------------------------------
// fp32 -> f16 conversion (per-float4 chunks)
// ---------------------------------------------------------------------------
__global__ __launch_bounds__(256)
void cvt_f16_kernel(const float* __restrict__ in, _Float16* __restrict__ out,
                    int n4) {
    int i = blockIdx.x * blockDim.x + threadIdx.x;
    if (i < n4) {
        float4 v = ((const float4*)in)[i];
        half4v o;
        o.x = (_Float16)v.x; o.y = (_Float16)v.y;
        o.z = (_Float16)v.z; o.w = (_Float16)v.w;
        ((half4v*)out)[i] = o;
    }
}

// ---------------------------------------------------------------------------
// LayerNorm + FiLM + seq_mask -> f16 output
// ---------------------------------------------------------------------------
__global__ __launch_bounds__(256)
void ln_film_kernel(const float* __restrict__ x,
                    const float* __restrict__ gamma,
                    const float* __restrict__ film,
                    const float* __restrict__ seq_mask,
                    _Float16* __restrict__ xnh) {
    int row = blockIdx.x;           // b*N + i
    int b = row >> 10;
    int t = threadIdx.x;
    const float* xr = x + (size_t)row * D_;
    float v0 = xr[t];
    float v1 = xr[t + 256];
    float s = v0 + v1;
    float sq = v0 * v0 + v1 * v1;
    int lane = t & 63, wave = t >> 6;
    #pragma unroll
    for (int off = 32; off; off >>= 1) {
        s  += __shfl_down(s, off);
        sq += __shfl_down(sq, off);
    }
    __shared__ float rs[4], rq[4];
    if (lane == 0) { rs[wave] = s; rq[wave] = sq; }
    __syncthreads();
    float mu  = (rs[0] + rs[1] + rs[2] + rs[3]) * (1.f / D_);
    float ex2 = (rq[0] + rq[1] + rq[2] + rq[3]) * (1.f / D_);
    float var = ex2 - mu * mu;
    float rstd = rsqrtf(var + EPS_);
    float mrow = seq_mask[row];
    const float* scale = film + (size_t)b * 2 * D_;
    const float* shift = scale + D_;
    {
        int d = t;
        float val = (v0 - mu) * rstd * gamma[d];
        val = val * (scale[d] + 1.f) + shift[d];
        xnh[(size_t)row * D_ + d] = (_Float16)(val * mrow);
    }
    {
        int d = t + 256;
        float val = (v1 - mu) * rstd * gamma[d];
        val = val * (scale[d] + 1.f) + shift[d];
        xnh[(size_t)row * D_ + d] = (_Float16)(val * mrow);
    }
}

// ---------------------------------------------------------------------------
// MFMA f16 GEMM:  C[M,Nn] = A[M,K] @ Bt[Nn,K]^T   (A,Bt f16; C fp32)
// 128x128 tile, BK=32, 256 threads = 4 waves, each wave 64x64 (4x4 MFMA 16x16x32)
// LDS row stride 40 halves (80 B): rows 0-7 hit all 32 banks once, 8-15 alias
// 2-way (free).  Per K-iter per wave: 16 MFMA + 8 ds_read_b128.
// ---------------------------------------------------------------------------
#define LDK 40
__global__ __launch_bounds__(256)
void gemm_mfma_f16(const _Float16* __restrict__ A,
                   const _Float16* __restrict__ Bt,
                   float* __restrict__ C,
                   int M, int Nn, int K) {
    __shared__ _Float16 As[128 * LDK];
    __shared__ _Float16 Bs[128 * LDK];
    int t = threadIdx.x;
    int wave = t >> 6, lane = t & 63;
    int quad = lane >> 4, l16 = lane & 15;
    int m0 = blockIdx.y * 128, n0 = blockIdx.x * 128;
    int wm = (wave >> 1) * 64, wn = (wave & 1) * 64;

    floatx4 acc[4][4];
    #pragma unroll
    for (int i = 0; i < 4; ++i)
        #pragma unroll
        for (int j = 0; j < 4; ++j)
            acc[i][j] = (floatx4){0.f, 0.f, 0.f, 0.f};

    int row0 = t >> 2;                 // 0..63
    int seg0 = (t & 3) * 8;            // halves within BK

    for (int k0 = 0; k0 < K; k0 += 32) {
        half8v a0 = *(const half8v*)(A  + (size_t)(m0 + row0)      * K + k0 + seg0);
        half8v a1 = *(const half8v*)(A  + (size_t)(m0 + row0 + 64) * K + k0 + seg0);
        half8v b0 = *(const half8v*)(Bt + (size_t)(n0 + row0)      * K + k0 + seg0);
        half8v b1 = *(const half8v*)(Bt + (size_t)(n0 + row0 + 64) * K + k0 + seg0);
        __syncthreads();   // previous-iter fragment reads complete
        *(half8v*)(As + row0 * LDK + seg0)        = a0;
        *(half8v*)(As + (row0 + 64) * LDK + seg0) = a1;
        *(half8v*)(Bs + row0 * LDK + seg0)        = b0;
        *(half8v*)(Bs + (row0 + 64) * LDK + seg0) = b1;
        __syncthreads();   // staging visible

        half8v af[4], bf[4];
        #pragma unroll
        for (int i = 0; i < 4; ++i)
            af[i] = *(half8v*)(As + (wm + i * 16 + l16) * LDK + quad * 8);
        #pragma unroll
        for (int j = 0; j < 4; ++j)
            bf[j] = *(half8v*)(Bs + (wn + j * 16 + l16) * LDK + quad * 8);
        #pragma unroll
        for (int i = 0; i < 4; ++i)
            #pragma unroll
            for (int j = 0; j < 4; ++j)
                acc[i][j] = __builtin_amdgcn_mfma_f32_16x16x32_f16(
                    af[i], bf[j], acc[i][j], 0, 0, 0);
    }

    // C/D layout: col = lane&15, row = quad*4 + reg   [m89/m91 verified]
    #pragma unroll
    for (int i = 0; i < 4; ++i)
        #pragma unroll
        for (int j = 0; j < 4; ++j)
            #pragma unroll
            for (int r = 0; r < 4; ++r) {
                int grow = m0 + wm + i * 16 + quad * 4 + r;
                int gcol = n0 + wn + j * 16 + l16;
                C[(size_t)grow * Nn + gcol] = acc[i][j][r];
            }
}

// ---------------------------------------------------------------------------
// bias projection: pb[b,h,i,j] = sum_a attn_bias[b,a,i,j]*Wb[h,a] + bb[h]
//                                - (1 - mq*mk)*NEG          (stored as bf16)
// ---------------------------------------------------------------------------
__global__ __launch_bounds__(256)
void bias_proj_kernel(const float* __restrict__ ab,
                      const float* __restrict__ seq_mask,
                      const float* __restrict__ Wb,
                      const float* __restrict__ bb,
                      __hip_bfloat16* __restrict__ pb) {
    __shared__ float wbs[8][16];
    __shared__ float bbs[8];
    int blk = blockIdx.x;      // b*1024 + i
    int b = blk >> 10;
    int i = blk & 1023;
    int t = threadIdx.x;
    if (t < 128) wbs[t >> 4][t & 15] = Wb[t];
    if (t < 8)   bbs[t] = bb[t];
    __syncthreads();

    float accx[8], accy[8], accz[8], accw[8];
    #pragma unroll
    for (int h = 0; h < 8; ++h) { accx[h] = accy[h] = accz[h] = accw[h] = bbs[h]; }

    const float* base = ab + ((size_t)(b * AB_) * N_ + i) * N_ + t * 4;
    #pragma unroll
    for (int a = 0; a < AB_; ++a) {
        float4 v = *(const float4*)(base + (size_t)a * N_ * N_);
        #pragma unroll
        for (int h = 0; h < 8; ++h) {
            float w = wbs[h][a];
            accx[h] += v.x * w;
            accy[h] += v.y * w;
            accz[h] += v.z * w;
            accw[h] += v.w * w;
        }
    }
    float mq = seq_mask[blk];
    float4 mk = *(const float4*)(seq_mask + b * N_ + t * 4);
    float px = (1.f - mq * mk.x) * NEG_;
    float py = (1.f - mq * mk.y) * NEG_;
    float pz = (1.f - mq * mk.z) * NEG_;
    float pw = (1.f - mq * mk.w) * NEG_;

    #pragma unroll
    for (int h = 0; h < 8; ++h) {
        __hip_bfloat16 tmp[4];
        tmp[0] = __float2bfloat16(accx[h] - px);
        tmp[1] = __float2bfloat16(accy[h] - py);
        tmp[2] = __float2bfloat16(accz[h] - pz);
        tmp[3] = __float2bfloat16(accw[h] - pw);
        size_t off = (((size_t)(b * 8 + h) * N_) + i) * N_ + t * 4;
        *(ushort4*)(pb + off) = *(ushort4*)tmp;
    }
}

// ---------------------------------------------------------------------------
// Flash attention: one block per (b, h, 64-query tile). Online softmax.
// Writes att as f16 with seq_mask folded in (feeds the MFMA out-gemm).
// ---------------------------------------------------------------------------
#define LDST 68
__global__ __launch_bounds__(256, 2)
void flash_attn_kernel(const float* __restrict__ q,
                       const float* __restrict__ kv,
                       const __hip_bfloat16* __restrict__ pb,
                       const float* __restrict__ seq_mask,
                       _Float16* __restrict__ atth) {
    __shared__ float Qs[64][LDST];
    __shared__ float Ks[64][LDST];
    __shared__ float Vs[64][LDST];
    __shared__ float Ps[64][LDST];

    int z  = blockIdx.x;
    int it = z & 15;
    int h  = (z >> 4) & 7;
    int b  = z >> 7;
    int i0 = it * 64;
    int t  = threadIdx.x;
    int tx = t & 15;
    int ty = t >> 4;

    // stage Q tile (scaled by DH^-0.5 = 1/8)
    const float* qbase = q + ((size_t)(b * N_ + i0)) * 512 + h * 64;
    #pragma unroll
    for (int l = 0; l < 4; ++l) {
        int idx = l * 256 + t;
        int r   = idx >> 4;
        int c4  = (idx & 15) * 4;
        float4 v = *(const float4*)(qbase + (size_t)r * 512 + c4);
        v.x *= 0.125f; v.y *= 0.125f; v.z *= 0.125f; v.w *= 0.125f;
        *(float4*)&Qs[r][c4] = v;
    }

    float m_r[4], l_r[4], c_o[4][4];
    #pragma unroll
    for (int i = 0; i < 4; ++i) {
        m_r[i] = -1e30f; l_r[i] = 0.f;
        #pragma unroll
        for (int d = 0; d < 4; ++d) c_o[i][d] = 0.f;
    }

    const float* kvbase = kv + (size_t)b * N_ * 1024 + h * 64;
    const __hip_bfloat16* pbbase = pb + ((size_t)((b * 8 + h) * N_) + i0) * N_;

    for (int jt = 0; jt < 16; ++jt) {
        int j0 = jt * 64;
        float4 kreg[4], vreg[4];
        #pragma unroll
        for (int l = 0; l < 4; ++l) {
            int idx = l * 256 + t;
            int r   = idx >> 4;
            int c4  = (idx & 15) * 4;
            const float* p = kvbase + (size_t)(j0 + r) * 1024 + c4;
            kreg[l] = *(const float4*)p;
            vreg[l] = *(const float4*)(p + 512);
        }
        float sreg[4][4];
        #pragma unroll
        for (int i = 0; i < 4; ++i)
            #pragma unroll
            for (int jj = 0; jj < 4; ++jj)
                sreg[i][jj] = __bfloat162float(
                    pbbase[(size_t)(ty * 4 + i) * N_ + j0 + tx + jj * 16]);

        __syncthreads();
        #pragma unroll
        for (int l = 0; l < 4; ++l) {
            int idx = l * 256 + t;
            int r   = idx >> 4;
            int c4  = (idx & 15) * 4;
            *(float4*)&Ks[r][c4] = kreg[l];
            *(float4*)&Vs[r][c4] = vreg[l];
        }
        __syncthreads();

        // ---- S = Q K^T + bias ----
        #pragma unroll
        for (int d0 = 0; d0 < 64; d0 += 4) {
            float4 a4[4], b4[4];
            #pragma unroll
            for (int i = 0; i < 4; ++i) a4[i] = *(float4*)&Qs[ty * 4 + i][d0];
            #pragma unroll
            for (int jj = 0; jj < 4; ++jj) b4[jj] = *(float4*)&Ks[tx + jj * 16][d0];
            #pragma unroll
            for (int i = 0; i < 4; ++i)
                #pragma unroll
                for (int jj = 0; jj < 4; ++jj)
                    sreg[i][jj] += a4[i].x * b4[jj].x + a4[i].y * b4[jj].y
                                 + a4[i].z * b4[jj].z + a4[i].w * b4[jj].w;
        }

        // ---- online softmax ----
        float rm[4], alpha[4], rsum[4], preg[4][4];
        #pragma unroll
        for (int i = 0; i < 4; ++i)
            rm[i] = fmaxf(fmaxf(sreg[i][0], sreg[i][1]),
                          fmaxf(sreg[i][2], sreg[i][3]));
        #pragma unroll
        for (int off = 1; off < 16; off <<= 1) {
            #pragma unroll
            for (int i = 0; i < 4; ++i)
                rm[i] = fmaxf(rm[i], __shfl_xor(rm[i], off));
        }
        #pragma unroll
        for (int i = 0; i < 4; ++i) {
            float mn = fmaxf(m_r[i], rm[i]);
            alpha[i] = __expf(m_r[i] - mn);
            m_r[i] = mn;
            float p0 = __expf(sreg[i][0] - mn);
            float p1 = __expf(sreg[i][1] - mn);
            float p2 = __expf(sreg[i][2] - mn);
            float p3 = __expf(sreg[i][3] - mn);
            preg[i][0] = p0; preg[i][1] = p1; preg[i][2] = p2; preg[i][3] = p3;
            rsum[i] = p0 + p1 + p2 + p3;
        }
        #pragma unroll
        for (int off = 1; off < 16; off <<= 1) {
            #pragma unroll
            for (int i = 0; i < 4; ++i)
                rsum[i] += __shfl_xor(rsum[i], off);
        }
        #pragma unroll
        for (int i = 0; i < 4; ++i) {
            l_r[i] = l_r[i] * alpha[i] + rsum[i];
            #pragma unroll
            for (int d = 0; d < 4; ++d) c_o[i][d] *= alpha[i];
            #pragma unroll
            for (int jj = 0; jj < 4; ++jj)
                Ps[ty * 4 + i][tx + jj * 16] = preg[i][jj];
        }
        __syncthreads();

        // ---- O += P @ V ----
        #pragma unroll 8
        for (int j = 0; j < 64; ++j) {
            float a_[4];
            #pragma unroll
            for (int i = 0; i < 4; ++i) a_[i] = Ps[ty * 4 + i][j];
            float4 bv = *(float4*)&Vs[j][tx * 4];
            #pragma unroll
            for (int i = 0; i < 4; ++i) {
                c_o[i][0] += a_[i] * bv.x;
                c_o[i][1] += a_[i] * bv.y;
                c_o[i][2] += a_[i] * bv.z;
                c_o[i][3] += a_[i] * bv.w;
            }
        }
    }

    // ---- epilogue: f16 store, seq_mask folded in ----
    #pragma unroll
    for (int i = 0; i < 4; ++i) {
        int row = i0 + ty * 4 + i;
        float msk = seq_mask[b * N_ + row];
        float inv = msk / l_r[i];
        half4v o;
        o.x = (_Float16)(c_o[i][0] * inv);
        o.y = (_Float16)(c_o[i][1] * inv);
        o.z = (_Float16)(c_o[i][2] * inv);
        o.w = (_Float16)(c_o[i][3] * inv);
        *(half4v*)(atth + ((size_t)(b * N_ + row)) * 512 + h * 64 + tx * 4) = o;
    }
}

// ---------------------------------------------------------------------------
extern "C" void kernel_launch(void* const* d_in, const int* in_sizes, int n_in,
                              void* d_out, int out_size, void* d_ws, size_t ws_size,
                              hipStream_t stream) {
    const float* x         = (const float*)d_in[0];
    const float* time_in   = (const float*)d_in[1];
    const float* attn_bias = (const float*)d_in[2];
    const float* seq_mask  = (const float*)d_in[3];
    const float* gamma     = (const float*)d_in[4];
    const float* Wt        = (const float*)d_in[5];
    const float* bt        = (const float*)d_in[6];
    const float* Wq        = (const float*)d_in[7];
    const float* Wkv       = (const float*)d_in[8];
    const float* Wo        = (const float*)d_in[9];
    const float* Wb        = (const float*)d_in[10];
    const float* bb        = (const float*)d_in[11];
    float* out = (float*)d_out;

    char* ws = (char*)d_ws;
    const size_t KB = 1024, MB = 1024 * 1024;
    float*     film = (float*)ws;                          // 16 KB
    _Float16*  xnh  = (_Float16*)(ws + 16 * KB);           // 4 MB  [4096,512]
    _Float16*  xh   = (_Float16*)(ws + 16 * KB + 4 * MB);  // 4 MB
    _Float16*  Wqh  = (_Float16*)(ws + 16 * KB + 8 * MB);  // 512 KB
    _Float16*  Wkvh = (_Float16*)(ws + 16 * KB + 8 * MB + 512 * KB);  // 1 MB
    _Float16*  Woh  = (_Float16*)(ws + 16 * KB + 9 * MB + 512 * KB);  // 512 KB
    float*     qb   = (float*)(ws + 16 * KB + 10 * MB);    // 8 MB  [4096,512]
    float*     kvb  = (float*)(ws + 16 * KB + 18 * MB);    // 16 MB [4096,1024]
    _Float16*  atth = (_Float16*)(ws + 16 * KB + 34 * MB); // 4 MB
    __hip_bfloat16* pb = (__hip_bfloat16*)(ws + 16 * KB + 38 * MB);  // 64 MB

    film_kernel<<<16, 256, 0, stream>>>(time_in, Wt, bt, film);
    ln_film_kernel<<<4096, 256, 0, stream>>>(x, gamma, film, seq_mask, xnh);
    cvt_f16_kernel<<<2048, 256, 0, stream>>>(x, xh, 4096 * 512 / 4);
    cvt_f16_kernel<<<256, 256, 0, stream>>>(Wq, Wqh, 512 * 512 / 4);
    cvt_f16_kernel<<<512, 256, 0, stream>>>(Wkv, Wkvh, 1024 * 512 / 4);
    cvt_f16_kernel<<<256, 256, 0, stream>>>(Wo, Woh, 512 * 512 / 4);

    dim3 gq(512 / 128, 4096 / 128);
    gemm_mfma_f16<<<gq, 256, 0, stream>>>(xnh, Wqh, qb, 4096, 512, 512);
    dim3 gkv(1024 / 128, 4096 / 128);
    gemm_mfma_f16<<<gkv, 256, 0, stream>>>(xh, Wkvh, kvb, 4096, 1024, 512);

    bias_proj_kernel<<<4096, 256, 0, stream>>>(attn_bias, seq_mask, Wb, bb, pb);
    flash_attn_kernel<<<512, 256, 0, stream>>>(qb, kvb, pb, seq_mask, atth);

    dim3 go(512 / 128, 4096 / 128);
    gemm_mfma_f16<<<go, 256, 0, stream>>>(atth, Woh, out, 4096, 512, 512);
}

// Round 5
// 531.198 us; speedup vs baseline: 5.2937x; 1.2741x over previous
//
#include <hip/hip_runtime.h>
#include <hip/hip_bf16.h>
#include <math.h>

#define B_  4
#define N_  1024
#define D_  512
#define H_  8
#define DH_ 64
#define TC_ 512
#define AB_ 16
#define EPS_ 1e-5f
#define NEG_ 1e6f

typedef _Float16 half8v __attribute__((ext_vector_type(8)));
typedef _Float16 half4v __attribute__((ext_vector_type(4)));
typedef float floatx4 __attribute__((ext_vector_type(4)));

// ---------------------------------------------------------------------------
// FiLM precompute: film[b, c] = sum_j silu(time[b, j]) * Wt[c, j] + bt[c]
// ---------------------------------------------------------------------------
__global__ void film_kernel(const float* __restrict__ time_in,
                            const float* __restrict__ Wt,
                            const float* __restrict__ bt,
                            float* __restrict__ film) {
    int idx = blockIdx.x * blockDim.x + threadIdx.x;   // 0 .. B*2D-1 = 4095
    int b = idx >> 10;
    int c = idx & 1023;
    const float* trow = time_in + b * TC_;
    const float* wrow = Wt + (size_t)c * TC_;
    float acc = bt[c];
    for (int j = 0; j < TC_; ++j) {
        float tv = trow[j];
        float s = tv / (1.f + __expf(-tv));   // silu
        acc += s * wrow[j];
    }
    film[idx] = acc;
}

// ---------------------------------------------------------------------------
// fp32 -> f16 conversion (per-float4 chunks)
// ---------------------------------------------------------------------------
__global__ __launch_bounds__(256)
void cvt_f16_kernel(const float* __restrict__ in, _Float16* __restrict__ out,
                    int n4) {
    int i = blockIdx.x * blockDim.x + threadIdx.x;
    if (i < n4) {
        float4 v = ((const float4*)in)[i];
        half4v o;
        o.x = (_Float16)v.x; o.y = (_Float16)v.y;
        o.z = (_Float16)v.z; o.w = (_Float16)v.w;
        ((half4v*)out)[i] = o;
    }
}

// ---------------------------------------------------------------------------
// LayerNorm + FiLM + seq_mask -> f16 output
// ---------------------------------------------------------------------------
__global__ __launch_bounds__(256)
void ln_film_kernel(const float* __restrict__ x,
                    const float* __restrict__ gamma,
                    const float* __restrict__ film,
                    const float* __restrict__ seq_mask,
                    _Float16* __restrict__ xnh) {
    int row = blockIdx.x;           // b*N + i
    int b = row >> 10;
    int t = threadIdx.x;
    const float* xr = x + (size_t)row * D_;
    float v0 = xr[t];
    float v1 = xr[t + 256];
    float s = v0 + v1;
    float sq = v0 * v0 + v1 * v1;
    int lane = t & 63, wave = t >> 6;
    #pragma unroll
    for (int off = 32; off; off >>= 1) {
        s  += __shfl_down(s, off);
        sq += __shfl_down(sq, off);
    }
    __shared__ float rs[4], rq[4];
    if (lane == 0) { rs[wave] = s; rq[wave] = sq; }
    __syncthreads();
    float mu  = (rs[0] + rs[1] + rs[2] + rs[3]) * (1.f / D_);
    float ex2 = (rq[0] + rq[1] + rq[2] + rq[3]) * (1.f / D_);
    float var = ex2 - mu * mu;
    float rstd = rsqrtf(var + EPS_);
    float mrow = seq_mask[row];
    const float* scale = film + (size_t)b * 2 * D_;
    const float* shift = scale + D_;
    {
        int d = t;
        float val = (v0 - mu) * rstd * gamma[d];
        val = val * (scale[d] + 1.f) + shift[d];
        xnh[(size_t)row * D_ + d] = (_Float16)(val * mrow);
    }
    {
        int d = t + 256;
        float val = (v1 - mu) * rstd * gamma[d];
        val = val * (scale[d] + 1.f) + shift[d];
        xnh[(size_t)row * D_ + d] = (_Float16)(val * mrow);
    }
}

// ---------------------------------------------------------------------------
// MFMA f16 GEMM:  C[M,Nn] = A[M,K] @ Bt[Nn,K]^T   (A,Bt f16; C fp32)
// 128x128 tile, BK=32, 256 threads = 4 waves, each wave 64x64 (4x4 MFMA 16x16x32)
// ---------------------------------------------------------------------------
#define LDK 40
__global__ __launch_bounds__(256)
void gemm_mfma_f16(const _Float16* __restrict__ A,
                   const _Float16* __restrict__ Bt,
                   float* __restrict__ C,
                   int M, int Nn, int K) {
    __shared__ _Float16 As[128 * LDK];
    __shared__ _Float16 Bs[128 * LDK];
    int t = threadIdx.x;
    int wave = t >> 6, lane = t & 63;
    int quad = lane >> 4, l16 = lane & 15;
    int m0 = blockIdx.y * 128, n0 = blockIdx.x * 128;
    int wm = (wave >> 1) * 64, wn = (wave & 1) * 64;

    floatx4 acc[4][4];
    #pragma unroll
    for (int i = 0; i < 4; ++i)
        #pragma unroll
        for (int j = 0; j < 4; ++j)
            acc[i][j] = (floatx4){0.f, 0.f, 0.f, 0.f};

    int row0 = t >> 2;                 // 0..63
    int seg0 = (t & 3) * 8;            // halves within BK

    for (int k0 = 0; k0 < K; k0 += 32) {
        half8v a0 = *(const half8v*)(A  + (size_t)(m0 + row0)      * K + k0 + seg0);
        half8v a1 = *(const half8v*)(A  + (size_t)(m0 + row0 + 64) * K + k0 + seg0);
        half8v b0 = *(const half8v*)(Bt + (size_t)(n0 + row0)      * K + k0 + seg0);
        half8v b1 = *(const half8v*)(Bt + (size_t)(n0 + row0 + 64) * K + k0 + seg0);
        __syncthreads();   // previous-iter fragment reads complete
        *(half8v*)(As + row0 * LDK + seg0)        = a0;
        *(half8v*)(As + (row0 + 64) * LDK + seg0) = a1;
        *(half8v*)(Bs + row0 * LDK + seg0)        = b0;
        *(half8v*)(Bs + (row0 + 64) * LDK + seg0) = b1;
        __syncthreads();   // staging visible

        half8v af[4], bf[4];
        #pragma unroll
        for (int i = 0; i < 4; ++i)
            af[i] = *(half8v*)(As + (wm + i * 16 + l16) * LDK + quad * 8);
        #pragma unroll
        for (int j = 0; j < 4; ++j)
            bf[j] = *(half8v*)(Bs + (wn + j * 16 + l16) * LDK + quad * 8);
        #pragma unroll
        for (int i = 0; i < 4; ++i)
            #pragma unroll
            for (int j = 0; j < 4; ++j)
                acc[i][j] = __builtin_amdgcn_mfma_f32_16x16x32_f16(
                    af[i], bf[j], acc[i][j], 0, 0, 0);
    }

    // C/D layout: col = lane&15, row = quad*4 + reg
    #pragma unroll
    for (int i = 0; i < 4; ++i)
        #pragma unroll
        for (int j = 0; j < 4; ++j)
            #pragma unroll
            for (int r = 0; r < 4; ++r) {
                int grow = m0 + wm + i * 16 + quad * 4 + r;
                int gcol = n0 + wn + j * 16 + l16;
                C[(size_t)grow * Nn + gcol] = acc[i][j][r];
            }
}

// ---------------------------------------------------------------------------
// bias projection: pb[b,h,i,j] = sum_a attn_bias[b,a,i,j]*Wb[h,a] + bb[h]
//                                - (1 - mq*mk)*NEG          (stored as bf16)
// ---------------------------------------------------------------------------
__global__ __launch_bounds__(256)
void bias_proj_kernel(const float* __restrict__ ab,
                      const float* __restrict__ seq_mask,
                      const float* __restrict__ Wb,
                      const float* __restrict__ bb,
                      __hip_bfloat16* __restrict__ pb) {
    __shared__ float wbs[8][16];
    __shared__ float bbs[8];
    int blk = blockIdx.x;      // b*1024 + i
    int b = blk >> 10;
    int i = blk & 1023;
    int t = threadIdx.x;
    if (t < 128) wbs[t >> 4][t & 15] = Wb[t];
    if (t < 8)   bbs[t] = bb[t];
    __syncthreads();

    float accx[8], accy[8], accz[8], accw[8];
    #pragma unroll
    for (int h = 0; h < 8; ++h) { accx[h] = accy[h] = accz[h] = accw[h] = bbs[h]; }

    const float* base = ab + ((size_t)(b * AB_) * N_ + i) * N_ + t * 4;
    #pragma unroll
    for (int a = 0; a < AB_; ++a) {
        float4 v = *(const float4*)(base + (size_t)a * N_ * N_);
        #pragma unroll
        for (int h = 0; h < 8; ++h) {
            float w = wbs[h][a];
            accx[h] += v.x * w;
            accy[h] += v.y * w;
            accz[h] += v.z * w;
            accw[h] += v.w * w;
        }
    }
    float mq = seq_mask[blk];
    float4 mk = *(const float4*)(seq_mask + b * N_ + t * 4);
    float px = (1.f - mq * mk.x) * NEG_;
    float py = (1.f - mq * mk.y) * NEG_;
    float pz = (1.f - mq * mk.z) * NEG_;
    float pw = (1.f - mq * mk.w) * NEG_;

    #pragma unroll
    for (int h = 0; h < 8; ++h) {
        __hip_bfloat16 tmp[4];
        tmp[0] = __float2bfloat16(accx[h] - px);
        tmp[1] = __float2bfloat16(accy[h] - py);
        tmp[2] = __float2bfloat16(accz[h] - pz);
        tmp[3] = __float2bfloat16(accw[h] - pw);
        size_t off = (((size_t)(b * 8 + h) * N_) + i) * N_ + t * 4;
        *(ushort4*)(pb + off) = *(ushort4*)tmp;
    }
}

// ---------------------------------------------------------------------------
// MFMA flash attention: one block per (b, h, 64-query tile), 4 waves.
// Each wave owns a 16-row strip. S = QK^T via mfma_f32_16x16x32_f16 with the
// accumulator initialized from pb (bias+mask, C-layout). Online softmax on
// C-fragments; P round-trips through LDS (f16, A-layout); V transposed in LDS
// for the B-operand. Strides: Qs/Ks/Ps 72 halves (b128-aligned, 2-way banks),
// Vt 68 halves (b64 reads).
// ---------------------------------------------------------------------------
#define LDF 72
#define LDP 72
#define LDV 68
__global__ __launch_bounds__(256, 4)
void flash_mfma_kernel(const float* __restrict__ q,
                       const float* __restrict__ kv,
                       const __hip_bfloat16* __restrict__ pb,
                       const float* __restrict__ seq_mask,
                       _Float16* __restrict__ atth) {
    __shared__ _Float16 Qs[64 * LDF];
    __shared__ _Float16 Ks[64 * LDF];
    __shared__ _Float16 Ps[64 * LDP];
    __shared__ _Float16 Vt[64 * LDV];

    int z  = blockIdx.x;
    int qt = z & 15;
    int h  = (z >> 4) & 7;
    int b  = z >> 7;
    int i0 = qt * 64;
    int t  = threadIdx.x;
    int wave = t >> 6, lane = t & 63;
    int quad = lane >> 4, l16 = lane & 15;
    int strip = wave * 16;

    // ---- stage Q tile as f16, pre-scaled by DH^-0.5 = 1/8 ----
    const float* qbase = q + ((size_t)(b * N_ + i0)) * 512 + h * 64;
    #pragma unroll
    for (int l = 0; l < 4; ++l) {
        int idx = l * 256 + t;
        int r = idx >> 4, c4 = (idx & 15) * 4;
        float4 v = *(const float4*)(qbase + (size_t)r * 512 + c4);
        half4v o;
        o.x = (_Float16)(v.x * 0.125f);
        o.y = (_Float16)(v.y * 0.125f);
        o.z = (_Float16)(v.z * 0.125f);
        o.w = (_Float16)(v.w * 0.125f);
        *(half4v*)&Qs[r * LDF + c4] = o;
    }
    __syncthreads();
    half8v qf[2];
    qf[0] = *(half8v*)&Qs[(strip + l16) * LDF + quad * 8];
    qf[1] = *(half8v*)&Qs[(strip + l16) * LDF + 32 + quad * 8];

    float m_r[4], l_r[4];
    floatx4 acco[4];
    #pragma unroll
    for (int r = 0; r < 4; ++r) { m_r[r] = -1e30f; l_r[r] = 0.f; }
    #pragma unroll
    for (int tile = 0; tile < 4; ++tile)
        acco[tile] = (floatx4){0.f, 0.f, 0.f, 0.f};

    const float* kvbase = kv + (size_t)b * N_ * 1024 + h * 64;
    const __hip_bfloat16* pbb =
        pb + ((size_t)((b * 8 + h) * N_) + i0 + strip + quad * 4) * N_;

    for (int jt = 0; jt < 16; ++jt) {
        int j0 = jt * 64;
        // ---- global prefetch into regs ----
        float4 kreg[4], vreg[4];
        #pragma unroll
        for (int l = 0; l < 4; ++l) {
            int idx = l * 256 + t;
            int r = idx >> 4, c4 = (idx & 15) * 4;
            const float* p = kvbase + (size_t)(j0 + r) * 1024 + c4;
            kreg[l] = *(const float4*)p;
            vreg[l] = *(const float4*)(p + 512);
        }
        // S accumulator init = bias (C-layout: row=quad*4+r, col=tile*16+l16)
        floatx4 accs[4];
        #pragma unroll
        for (int tile = 0; tile < 4; ++tile)
            #pragma unroll
            for (int r = 0; r < 4; ++r)
                accs[tile][r] = __bfloat162float(
                    pbb[(size_t)r * N_ + j0 + tile * 16 + l16]);

        __syncthreads();   // prev iter's Ks/Vt/Ps reads complete
        #pragma unroll
        for (int l = 0; l < 4; ++l) {
            int idx = l * 256 + t;
            int r = idx >> 4, c4 = (idx & 15) * 4;
            half4v kh;
            kh.x = (_Float16)kreg[l].x;
            kh.y = (_Float16)kreg[l].y;
            kh.z = (_Float16)kreg[l].z;
            kh.w = (_Float16)kreg[l].w;
            *(half4v*)&Ks[r * LDF + c4] = kh;
            Vt[(c4 + 0) * LDV + r] = (_Float16)vreg[l].x;
            Vt[(c4 + 1) * LDV + r] = (_Float16)vreg[l].y;
            Vt[(c4 + 2) * LDV + r] = (_Float16)vreg[l].z;
            Vt[(c4 + 3) * LDV + r] = (_Float16)vreg[l].w;
        }
        __syncthreads();   // staging visible

        // ---- S = QK^T + bias via MFMA ----
        #pragma unroll
        for (int c = 0; c < 2; ++c)
            #pragma unroll
            for (int tile = 0; tile < 4; ++tile) {
                half8v kf = *(half8v*)&Ks[(tile * 16 + l16) * LDF + c * 32 + quad * 8];
                accs[tile] = __builtin_amdgcn_mfma_f32_16x16x32_f16(
                    qf[c], kf, accs[tile], 0, 0, 0);
            }

        // ---- online softmax on C-fragments ----
        float rm[4];
        #pragma unroll
        for (int r = 0; r < 4; ++r)
            rm[r] = fmaxf(fmaxf(accs[0][r], accs[1][r]),
                          fmaxf(accs[2][r], accs[3][r]));
        #pragma unroll
        for (int off = 1; off < 16; off <<= 1)
            #pragma unroll
            for (int r = 0; r < 4; ++r)
                rm[r] = fmaxf(rm[r], __shfl_xor(rm[r], off));
        float alpha[4], rsum[4], pv[4][4];
        #pragma unroll
        for (int r = 0; r < 4; ++r) {
            float mn = fmaxf(m_r[r], rm[r]);
            alpha[r] = __expf(m_r[r] - mn);
            m_r[r] = mn;
            float s = 0.f;
            #pragma unroll
            for (int tile = 0; tile < 4; ++tile) {
                float e = __expf(accs[tile][r] - mn);
                pv[tile][r] = e;
                s += e;
            }
            rsum[r] = s;
        }
        #pragma unroll
        for (int off = 1; off < 16; off <<= 1)
            #pragma unroll
            for (int r = 0; r < 4; ++r)
                rsum[r] += __shfl_xor(rsum[r], off);
        #pragma unroll
        for (int r = 0; r < 4; ++r) {
            l_r[r] = l_r[r] * alpha[r] + rsum[r];
            #pragma unroll
            for (int tile = 0; tile < 4; ++tile) {
                acco[tile][r] *= alpha[r];
                Ps[(strip + quad * 4 + r) * LDP + tile * 16 + l16] =
                    (_Float16)pv[tile][r];
            }
        }
        __syncthreads();   // Ps visible

        // ---- O += P @ V via MFMA (A = P, B = Vt) ----
        #pragma unroll
        for (int c = 0; c < 2; ++c) {
            half8v pf = *(half8v*)&Ps[(strip + l16) * LDP + c * 32 + quad * 8];
            #pragma unroll
            for (int tile = 0; tile < 4; ++tile) {
                union { half8v v8; half4v v4[2]; } vu;
                int vbase = (tile * 16 + l16) * LDV + c * 32 + quad * 8;
                vu.v4[0] = *(half4v*)&Vt[vbase];
                vu.v4[1] = *(half4v*)&Vt[vbase + 4];
                acco[tile] = __builtin_amdgcn_mfma_f32_16x16x32_f16(
                    pf, vu.v8, acco[tile], 0, 0, 0);
            }
        }
    }

    // ---- epilogue: normalize, mask, f16 store ----
    #pragma unroll
    for (int r = 0; r < 4; ++r) {
        int row = i0 + strip + quad * 4 + r;
        float msk = seq_mask[b * N_ + row];
        float inv = msk / l_r[r];
        _Float16* ob = atth + ((size_t)(b * N_ + row)) * 512 + h * 64;
        #pragma unroll
        for (int tile = 0; tile < 4; ++tile)
            ob[tile * 16 + l16] = (_Float16)(acco[tile][r] * inv);
    }
}

// ---------------------------------------------------------------------------
extern "C" void kernel_launch(void* const* d_in, const int* in_sizes, int n_in,
                              void* d_out, int out_size, void* d_ws, size_t ws_size,
                              hipStream_t stream) {
    const float* x         = (const float*)d_in[0];
    const float* time_in   = (const float*)d_in[1];
    const float* attn_bias = (const float*)d_in[2];
    const float* seq_mask  = (const float*)d_in[3];
    const float* gamma     = (const float*)d_in[4];
    const float* Wt        = (const float*)d_in[5];
    const float* bt        = (const float*)d_in[6];
    const float* Wq        = (const float*)d_in[7];
    const float* Wkv       = (const float*)d_in[8];
    const float* Wo        = (const float*)d_in[9];
    const float* Wb        = (const float*)d_in[10];
    const float* bb        = (const float*)d_in[11];
    float* out = (float*)d_out;

    char* ws = (char*)d_ws;
    const size_t KB = 1024, MB = 1024 * 1024;
    float*     film = (float*)ws;                          // 16 KB
    _Float16*  xnh  = (_Float16*)(ws + 16 * KB);           // 4 MB  [4096,512]
    _Float16*  xh   = (_Float16*)(ws + 16 * KB + 4 * MB);  // 4 MB
    _Float16*  Wqh  = (_Float16*)(ws + 16 * KB + 8 * MB);  // 512 KB
    _Float16*  Wkvh = (_Float16*)(ws + 16 * KB + 8 * MB + 512 * KB);  // 1 MB
    _Float16*  Woh  = (_Float16*)(ws + 16 * KB + 9 * MB + 512 * KB);  // 512 KB
    float*     qb   = (float*)(ws + 16 * KB + 10 * MB);    // 8 MB  [4096,512]
    float*     kvb  = (float*)(ws + 16 * KB + 18 * MB);    // 16 MB [4096,1024]
    _Float16*  atth = (_Float16*)(ws + 16 * KB + 34 * MB); // 4 MB
    __hip_bfloat16* pb = (__hip_bfloat16*)(ws + 16 * KB + 38 * MB);  // 64 MB

    film_kernel<<<16, 256, 0, stream>>>(time_in, Wt, bt, film);
    ln_film_kernel<<<4096, 256, 0, stream>>>(x, gamma, film, seq_mask, xnh);
    cvt_f16_kernel<<<2048, 256, 0, stream>>>(x, xh, 4096 * 512 / 4);
    cvt_f16_kernel<<<256, 256, 0, stream>>>(Wq, Wqh, 512 * 512 / 4);
    cvt_f16_kernel<<<512, 256, 0, stream>>>(Wkv, Wkvh, 1024 * 512 / 4);
    cvt_f16_kernel<<<256, 256, 0, stream>>>(Wo, Woh, 512 * 512 / 4);

    dim3 gq(512 / 128, 4096 / 128);
    gemm_mfma_f16<<<gq, 256, 0, stream>>>(xnh, Wqh, qb, 4096, 512, 512);
    dim3 gkv(1024 / 128, 4096 / 128);
    gemm_mfma_f16<<<gkv, 256, 0, stream>>>(xh, Wkvh, kvb, 4096, 1024, 512);

    bias_proj_kernel<<<4096, 256, 0, stream>>>(attn_bias, seq_mask, Wb, bb, pb);
    flash_mfma_kernel<<<512, 256, 0, stream>>>(qb, kvb, pb, seq_mask, atth);

    dim3 go(512 / 128, 4096 / 128);
    gemm_mfma_f16<<<go, 256, 0, stream>>>(atth, Woh, out, 4096, 512, 512);
}